// Round 3
// baseline (389.135 us; speedup 1.0000x reference)
//
#include <hip/hip_runtime.h>

// Problem shapes (fixed by setup_inputs)
namespace {
constexpr int B  = 8;
constexpr int N  = 100;
constexpr int C  = 256;
constexpr int H  = 160;
constexpr int W  = 160;
constexpr int NC = 80;    // NUM_CLASSES
constexpr int PW = 164;   // padded LDS row stride (words); %4==0 keeps b128 alignment
constexpr int NSEG = W / 16; // 10 segments of 16 per row
constexpr int T  = 1024;  // 16 waves/block -> 16 waves/CU (was 4)
}

// image_h / image_w arrive as 1-element arrays of unknown dtype (python
// scalar). Read as int32; if implausible, reinterpret the bits as float32.
__device__ inline float read_dim(const int* p) {
    int i = *p;
    if (i >= 1 && i <= (1 << 26)) return (float)i;
    return __int_as_float(i);
}

extern "C" __global__ void __launch_bounds__(T)
vpe_kernel(const float* __restrict__ features,  // [B,C,H,W]
           const float* __restrict__ boxes,     // [B,N,4]
           const int*   __restrict__ gt,        // [B,N]
           const int*   __restrict__ neg_y,     // [B,NC]
           const int*   __restrict__ neg_x,     // [B,NC]
           const int*   __restrict__ imh_p,     // scalar
           const int*   __restrict__ imw_p,     // scalar
           float*       __restrict__ out)       // [B,NC,C]
{
    // One block per (b,c) plane. Row-wise segmented prefix sums only — the
    // column dimension is reduced directly per (box,row) work item, so no
    // full 2D SAT and no 160-long serial chains.
    __shared__ float P[H * PW];          // plane -> within-segment prefixes (~105 KB)
    __shared__ float segoff[H * NSEG];   // per-(row,seg): total, then exclusive offset
    __shared__ float cls_sum[NC];
    __shared__ int   cls_cnt[NC];
    __shared__ int   bx1[N], by1[N], bx2[N], by2[N], bcls[N];
    __shared__ float binv[N];

    const int tid = threadIdx.x;
    const int b   = blockIdx.x / C;
    const int c   = blockIdx.x % C;
    const float* plane = features + (size_t)(b * C + c) * (H * W);

    if (tid < NC) { cls_sum[tid] = 0.f; cls_cnt[tid] = 0; }

    // Box setup (uniform per b; recomputed per block — trivial cost).
    if (tid < N) {
        float imw = read_dim(imw_p), imh = read_dim(imh_p);
        float sx = (float)W / imw, sy = (float)H / imh;
        const float* bp = boxes + (size_t)(b * N + tid) * 4;
        int x1 = (int)fminf(fmaxf(floorf(bp[0] * sx), 0.f), (float)W);
        int y1 = (int)fminf(fmaxf(floorf(bp[1] * sy), 0.f), (float)H);
        int x2 = (int)fminf(fmaxf(floorf(bp[2] * sx), 0.f), (float)W);
        int y2 = (int)fminf(fmaxf(floorf(bp[3] * sy), 0.f), (float)H);
        bool valid = (x2 > x1) && (y2 > y1);
        bx1[tid] = x1; by1[tid] = y1; bx2[tid] = x2; by2[tid] = y2;
        int cls = gt[b * N + tid];
        bcls[tid] = valid ? cls : -1;
        binv[tid] = 1.f / (float)max((x2 - x1) * (y2 - y1), 1);
        if (valid) atomicAdd(&cls_cnt[cls], 1);
    }

    // Load: coalesced global float4 -> aligned LDS b128 (16 waves, ~6 loads
    // each in flight -> HBM-saturating).
    const float4* plane4 = (const float4*)plane;
    for (int i = tid; i < (H * W) / 4; i += T) {
        float4 v = plane4[i];
        int flat = i * 4;
        int y = flat / W, x = flat - y * W;
        *((float4*)&P[y * PW + x]) = v;
    }
    __syncthreads();

    // Row phase A: within-segment (16-elem) inclusive prefix in registers,
    // b128 LDS in/out; record segment totals. 1600 independent items.
    for (int it = tid; it < H * NSEG; it += T) {
        int y = it / NSEG, s = it - y * NSEG;
        float* base = &P[y * PW + s * 16];
        float4 a = ((float4*)base)[0], bq = ((float4*)base)[1],
               cq = ((float4*)base)[2], dq = ((float4*)base)[3];
        float v[16] = {a.x, a.y, a.z, a.w, bq.x, bq.y, bq.z, bq.w,
                       cq.x, cq.y, cq.z, cq.w, dq.x, dq.y, dq.z, dq.w};
        float run = 0.f;
        #pragma unroll
        for (int j = 0; j < 16; ++j) { run += v[j]; v[j] = run; }
        ((float4*)base)[0] = make_float4(v[0], v[1], v[2], v[3]);
        ((float4*)base)[1] = make_float4(v[4], v[5], v[6], v[7]);
        ((float4*)base)[2] = make_float4(v[8], v[9], v[10], v[11]);
        ((float4*)base)[3] = make_float4(v[12], v[13], v[14], v[15]);
        segoff[it] = run;   // segment total (for now)
    }
    __syncthreads();

    // Row phase B: exclusive prefix across each row's 10 segment totals
    // (10-long chain, one thread per row, in-place).
    if (tid < H) {
        float t_[NSEG];
        #pragma unroll
        for (int s = 0; s < NSEG; ++s) t_[s] = segoff[tid * NSEG + s];
        float run = 0.f;
        #pragma unroll
        for (int s = 0; s < NSEG; ++s) {
            float nv = run + t_[s];
            segoff[tid * NSEG + s] = run;
            run = nv;
        }
    }
    __syncthreads();

    // Box-row accumulation: 16000 (y, box) items over 1024 threads. Row-range
    // sum = p[x2-1] - p[x1-1], with p[x] = P[y][x] + segoff[y][x>>4] (segment
    // offsets folded into the lookup — no third sweep).
    for (int it = tid; it < H * N; it += T) {
        int y = it / N, n = it - y * N;
        int cls = bcls[n];
        if (cls >= 0 && y >= by1[n] && y < by2[n]) {
            int xr = bx2[n] - 1;
            float hi = P[y * PW + xr] + segoff[y * NSEG + (xr >> 4)];
            float lo = 0.f;
            int xl = bx1[n] - 1;
            if (xl >= 0) lo = P[y * PW + xl] + segoff[y * NSEG + (xl >> 4)];
            atomicAdd(&cls_sum[cls], (hi - lo) * binv[n]);
        }
    }
    __syncthreads();

    // Epilogue: mean or negative-pixel fallback; write column c of out[b,:,:].
    if (tid < NC) {
        int cnt = cls_cnt[tid];
        float v = (cnt > 0) ? cls_sum[tid] / (float)cnt
                            : plane[neg_y[b * NC + tid] * W + neg_x[b * NC + tid]];
        out[((size_t)b * NC + tid) * C + c] = v;
    }
}

extern "C" void kernel_launch(void* const* d_in, const int* in_sizes, int n_in,
                              void* d_out, int out_size, void* d_ws, size_t ws_size,
                              hipStream_t stream) {
    (void)in_sizes; (void)n_in; (void)d_ws; (void)ws_size; (void)out_size;
    vpe_kernel<<<dim3(B * C), dim3(T), 0, stream>>>(
        (const float*)d_in[0],   // features
        (const float*)d_in[1],   // boxes
        (const int*)d_in[2],     // gt_classes
        (const int*)d_in[3],     // neg_y
        (const int*)d_in[4],     // neg_x
        (const int*)d_in[5],     // image_h
        (const int*)d_in[6],     // image_w
        (float*)d_out);
}

// Round 4
// 309.337 us; speedup vs baseline: 1.2580x; 1.2580x over previous
//
#include <hip/hip_runtime.h>

// Problem shapes (fixed by setup_inputs)
namespace {
constexpr int B  = 8;
constexpr int N  = 100;
constexpr int C  = 256;
constexpr int H  = 160;
constexpr int W  = 160;
constexpr int NC = 80;     // NUM_CLASSES
constexpr int T  = 1024;   // threads/block = 16 waves
constexpr int NW = 16;     // waves/block
constexpr int RPW = H / NW;// 10 rows per wave
constexpr int SCR = 164;   // per-wave prefix scratch stride (floats)
}

// image_h / image_w arrive as 1-element arrays of unknown dtype (python
// scalar). Read as int32; if implausible, reinterpret the bits as float32.
__device__ inline float read_dim(const int* p) {
    int i = *p;
    if (i >= 1 && i <= (1 << 26)) return (float)i;
    return __int_as_float(i);
}

extern "C" __global__ void __launch_bounds__(T)
vpe_kernel(const float* __restrict__ features,  // [B,C,H,W]
           const float* __restrict__ boxes,     // [B,N,4]
           const int*   __restrict__ gt,        // [B,N]
           const int*   __restrict__ neg_y,     // [B,NC]
           const int*   __restrict__ neg_x,     // [B,NC]
           const int*   __restrict__ imh_p,     // scalar
           const int*   __restrict__ imw_p,     // scalar
           float*       __restrict__ out)       // [B,NC,C]
{
    // One block per (b,c). Wave-synchronous row pipeline: each wave owns 10
    // rows; row prefix sums live in registers + a tiny per-wave LDS scratch.
    // Each lane privately accumulates <=2 boxes in VGPRs (NO per-row atomics).
    __shared__ float rs[NW * SCR];     // 10.5 KB prefix scratch
    __shared__ float cls_sum[NC];
    __shared__ int   cls_cnt[NC];
    __shared__ int   bx1m[N], bx2m[N], by1[N], by2[N], bcls[N];
    __shared__ float bwgt[N];

    const int tid  = threadIdx.x;
    const int wave = tid >> 6, lane = tid & 63;
    const int b    = blockIdx.x / C;
    const int c    = blockIdx.x % C;
    const float* plane = features + (size_t)(b * C + c) * (H * W);

    if (tid < NC) { cls_sum[tid] = 0.f; cls_cnt[tid] = 0; }
    __syncthreads();

    // Box setup (uniform per b; recomputed per block — trivial cost).
    if (tid < N) {
        float imw = read_dim(imw_p), imh = read_dim(imh_p);
        float sx = (float)W / imw, sy = (float)H / imh;
        const float* bp = boxes + (size_t)(b * N + tid) * 4;
        int x1 = (int)fminf(fmaxf(floorf(bp[0] * sx), 0.f), (float)W);
        int y1 = (int)fminf(fmaxf(floorf(bp[1] * sy), 0.f), (float)H);
        int x2 = (int)fminf(fmaxf(floorf(bp[2] * sx), 0.f), (float)W);
        int y2 = (int)fminf(fmaxf(floorf(bp[3] * sy), 0.f), (float)H);
        bool valid = (x2 > x1) && (y2 > y1);
        bx1m[tid] = x1 - 1; bx2m[tid] = x2 - 1;
        by1[tid] = y1; by2[tid] = y2;
        int cls = gt[b * N + tid];
        bcls[tid] = valid ? cls : -1;
        bwgt[tid] = 1.f / (float)max((x2 - x1) * (y2 - y1), 1);
        if (valid) atomicAdd(&cls_cnt[cls], 1);
    }
    __syncthreads();
    // Fold the class-count divisor into the per-box weight.
    if (tid < N && bcls[tid] >= 0)
        bwgt[tid] /= (float)max(cls_cnt[bcls[tid]], 1);
    __syncthreads();

    // Per-lane box registers: lane owns boxes nA=lane and nB=lane+64.
    float* myrs = &rs[wave * SCR];
    const int nA = lane, nB = lane + 64;
    const int clsA = bcls[nA];
    const int y1A = by1[nA], y2A = by2[nA], x1A = bx1m[nA], x2A = bx2m[nA];
    const float wA = bwgt[nA];
    int clsB = -1, y1B = 0, y2B = 0, x1B = 0, x2B = 0; float wB = 0.f;
    if (nB < N) {
        clsB = bcls[nB]; y1B = by1[nB]; y2B = by2[nB];
        x1B = bx1m[nB]; x2B = bx2m[nB]; wB = bwgt[nB];
    }

    float accA = 0.f, accB = 0.f;
    const bool ldr = (lane < W / 4);   // 40 loader lanes cover one 640B row

    float4 v = ldr ? ((const float4*)(plane + (size_t)wave * W))[lane]
                   : make_float4(0.f, 0.f, 0.f, 0.f);
    for (int r = 0; r < RPW; ++r) {
        const int y = wave + (r << 4);
        // Prefetch next row before consuming this one.
        float4 vn = make_float4(0.f, 0.f, 0.f, 0.f);
        if (r + 1 < RPW && ldr)
            vn = ((const float4*)(plane + (size_t)(y + NW) * W))[lane];

        // In-wave inclusive prefix over the 160 row elements:
        // lane-local sum -> 6-step shuffle scan over lane totals -> local fixup.
        float t = v.x + v.y + v.z + v.w;
        float s = t;
        #pragma unroll
        for (int d = 1; d < 64; d <<= 1) {
            float u = __shfl_up(s, d, 64);
            if (lane >= d) s += u;
        }
        float e  = s - t;          // exclusive across lanes
        float p0 = e + v.x, p1 = p0 + v.y, p2 = p1 + v.z, p3 = p2 + v.w;
        if (ldr) *((float4*)(myrs + (lane << 2))) = make_float4(p0, p1, p2, p3);
        __builtin_amdgcn_wave_barrier();   // keep write before the gathers

        // Private per-lane box accumulation (no atomics).
        if (clsA >= 0 && y >= y1A && y < y2A) {
            float hi = myrs[x2A];
            float lo = (x1A >= 0) ? myrs[x1A] : 0.f;
            accA += hi - lo;
        }
        if (clsB >= 0 && y >= y1B && y < y2B) {
            float hi = myrs[x2B];
            float lo = (x1B >= 0) ? myrs[x1B] : 0.f;
            accB += hi - lo;
        }
        __builtin_amdgcn_wave_barrier();   // keep gathers before next overwrite
        v = vn;
    }

    // One atomic per (wave, box): 1600 per block total.
    if (clsA >= 0) atomicAdd(&cls_sum[clsA], accA * wA);
    if (clsB >= 0) atomicAdd(&cls_sum[clsB], accB * wB);
    __syncthreads();

    // Epilogue: mean (already /cnt via bwgt) or negative-pixel fallback.
    if (tid < NC) {
        int cnt = cls_cnt[tid];
        float o = (cnt > 0) ? cls_sum[tid]
                            : plane[neg_y[b * NC + tid] * W + neg_x[b * NC + tid]];
        out[((size_t)b * NC + tid) * C + c] = o;
    }
}

extern "C" void kernel_launch(void* const* d_in, const int* in_sizes, int n_in,
                              void* d_out, int out_size, void* d_ws, size_t ws_size,
                              hipStream_t stream) {
    (void)in_sizes; (void)n_in; (void)d_ws; (void)ws_size; (void)out_size;
    vpe_kernel<<<dim3(B * C), dim3(T), 0, stream>>>(
        (const float*)d_in[0],   // features
        (const float*)d_in[1],   // boxes
        (const int*)d_in[2],     // gt_classes
        (const int*)d_in[3],     // neg_y
        (const int*)d_in[4],     // neg_x
        (const int*)d_in[5],     // image_h
        (const int*)d_in[6],     // image_w
        (float*)d_out);
}